// Round 6
// baseline (1708.835 us; speedup 1.0000x reference)
//
#include <hip/hip_runtime.h>
#include <hip/hip_cooperative_groups.h>

namespace cg = cooperative_groups;

#define FLTMAX 3.402823466e+38f

// ---------------------------------------------------------------------------
// Geometry:
//   Layer1: B=1024, N=784, Np=896, S=7, F=512, I=8, K=4
//   Layer2: B=1024, N=512, Np=512, S=4, F=10,  I=8, K=4
// Layer-1 P planes are never materialized: cooperative kernel keeps them in
// registers (128 values/thread chip-wide = 67 MB per s-plane).
// ---------------------------------------------------------------------------

// xq1[b][n] = rint(clip(x,0,1)*255), padded to 896 with 0; sx1[b] = row sum.
// Also initializes stats1 (consumed only after this dispatch completes).
__global__ void prep1_kernel(const float* __restrict__ x, float* __restrict__ xq1,
                             float* __restrict__ sx1, unsigned* __restrict__ stats1)
{
    __shared__ float red[128];
    int b = blockIdx.x;
    if (blockIdx.x == 0) {
        for (int t = threadIdx.x; t < 224; t += 128) {
            stats1[t * 2] = 0x7F7FFFFFu; stats1[t * 2 + 1] = 0u;
        }
    }
    float psum = 0.f;
    for (int n = threadIdx.x; n < 896; n += 128) {
        float v = 0.f;
        if (n < 784) {
            float xv = x[b * 784 + n];
            xv = fminf(fmaxf(xv, 0.f), 1.f);
            v = rintf(__fmul_rn(xv, 255.f));
        }
        xq1[b * 896 + n] = v;
        psum += v;  // integer-valued, exact in any order
    }
    red[threadIdx.x] = psum;
    __syncthreads();
    for (int w = 64; w >= 1; w >>= 1) {
        if (threadIdx.x < w) red[threadIdx.x] += red[threadIdx.x + w];
        __syncthreads();
    }
    if (threadIdx.x == 0) sx1[b] = red[0];
}

// Pack xq1 bits, transposed layout: xqbT[i][w][b] (w = 32-n-group).
// Thread reads 32 consecutive floats (coalesced per-thread), writes
// lane-consecutive b (coalesced).
__global__ void bitpackT_kernel(const float* __restrict__ xq1, unsigned* __restrict__ xqbT)
{
    int gid = blockIdx.x * 256 + threadIdx.x;   // 28*1024
    if (gid >= 28672) return;
    int w = gid >> 10, b = gid & 1023;
    unsigned words[8] = {0, 0, 0, 0, 0, 0, 0, 0};
    const float* src = &xq1[b * 896 + w * 32];
#pragma unroll 8
    for (int n = 0; n < 32; ++n) {
        int v = (int)src[n];
#pragma unroll
        for (int i = 0; i < 8; ++i) words[i] |= ((unsigned)((v >> i) & 1)) << n;
    }
#pragma unroll
    for (int i = 0; i < 8; ++i) xqbT[(i * 28 + w) * 1024 + b] = words[i];
}

// Fused conductance-prep + transpose: writes g1t[n][k*512+f] directly.
__global__ void prepg1t_kernel(const float* __restrict__ w1, const float* __restrict__ noise1,
                               float* __restrict__ g1t)
{
    __shared__ float t[4][32][33];
    const int n0 = blockIdx.x * 32, f0 = blockIdx.y * 32;
    const int tid = threadIdx.x;
    {
        int n = tid & 31, fi = tid >> 5;
#pragma unroll
        for (int p = 0; p < 4; ++p) {
            int f = p * 8 + fi;
            int gn = n0 + n, gf = f0 + f;
            float gv[4] = {0.f, 0.f, 0.f, 0.f};
            if (gn < 784) {
                float w = w1[gf * 784 + gn];
                float Xi = fminf(fmaxf(rintf(__fmul_rn(__fmul_rn(__fadd_rn(w, 1.f), 0.5f), 255.f)),
                                       0.f), 255.f);
                int xi = (int)Xi;
                float4 nz = *(const float4*)&noise1[(gf * 896 + gn) * 4];
                float nzv[4] = {nz.x, nz.y, nz.z, nz.w};
#pragma unroll
                for (int k = 0; k < 4; ++k) {
                    int slc = (xi >> (2 * k)) & 3;
                    float base = __fadd_rn(__fmul_rn((float)slc, 0.9f), 0.3f);
                    float nf = __fadd_rn(1.f, __fmul_rn(0.05f, nzv[k]));
                    gv[k] = __fmul_rn(base, nf);
                }
            }
#pragma unroll
            for (int k = 0; k < 4; ++k) t[k][n][f] = gv[k];
        }
    }
    __syncthreads();
    {
        int f = tid & 31, nn = tid >> 5;
#pragma unroll
        for (int p = 0; p < 4; ++p) {
            int n = p * 8 + nn;
#pragma unroll
            for (int k = 0; k < 4; ++k)
                g1t[(n0 + n) * 2048 + k * 512 + f0 + f] = t[k][n][f];
        }
    }
}

// g2t[n][k][f] layout for layer-2 matmul
__global__ void prepg2_kernel(const float* __restrict__ w3, const float* __restrict__ noise3,
                              float* __restrict__ g2t)
{
    int gid = blockIdx.x * 256 + threadIdx.x;
    if (gid >= 10 * 512) return;
    int f = gid / 512, n = gid % 512;
    float w = w3[f * 512 + n];
    float Xi = fminf(fmaxf(rintf(__fmul_rn(__fmul_rn(__fadd_rn(w, 1.f), 0.5f), 255.f)),
                           0.f), 255.f);
    int xi = (int)Xi;
#pragma unroll
    for (int k = 0; k < 4; ++k) {
        int slc = (xi >> (2 * k)) & 3;
        float base = __fadd_rn(__fmul_rn((float)slc, 0.9f), 0.3f);
        float nf = __fadd_rn(1.f, __fmul_rn(0.05f, noise3[(f * 512 + n) * 4 + k]));
        g2t[n * 40 + k * 10 + f] = __fmul_rn(base, nf);
    }
}

// Layer-1 dummy column from transposed bit-planes: D = 0.3*popc(128 bits).
__global__ void dqpopT_kernel(const unsigned* __restrict__ xqbT, float* __restrict__ Dq)
{
    __shared__ float red[512];
    const int i = blockIdx.x / 7, s = blockIdx.x % 7;
    const int tid = threadIdx.x;
    float D[4];
    float mn = FLTMAX, mx = -FLTMAX;
#pragma unroll
    for (int u = 0; u < 4; ++u) {
        int b = tid + u * 256;
        int c = 0;
#pragma unroll
        for (int w = 0; w < 4; ++w)
            c += __popc(xqbT[(i * 28 + s * 4 + w) * 1024 + b]);
        D[u] = __fmul_rn((float)c, 0.3f);
        mn = fminf(mn, D[u]);
        mx = fmaxf(mx, D[u]);
    }
    red[tid] = mn; red[256 + tid] = mx;
    __syncthreads();
    for (int w = 128; w >= 1; w >>= 1) {
        if (tid < w) {
            red[tid] = fminf(red[tid], red[tid + w]);
            red[256 + tid] = fmaxf(red[256 + tid], red[256 + tid + w]);
        }
        __syncthreads();
    }
    mn = red[0]; mx = red[256];
    float step = __fmul_rn(__fsub_rn(mx, mn), 0.03125f);
    if (step <= 0.f) step = 1.f;
#pragma unroll
    for (int u = 0; u < 4; ++u) {
        int b = tid + u * 256;
        float idx = fminf(fmaxf(floorf(__fdiv_rn(__fsub_rn(D[u], mn), step)), 0.f), 31.f);
        Dq[(i * 7 + s) * 1024 + b] = __fadd_rn(__fmul_rn(idx, step), mn);
    }
}

// Layer-2 dummy column from xqb2 ([i][b][16w] layout).
__global__ void dqpop_kernel(const unsigned* __restrict__ xqb, float* __restrict__ Dq,
                             int S, int wpr)
{
    __shared__ float red[512];
    const int i = blockIdx.x / S, s = blockIdx.x % S;
    const int tid = threadIdx.x;
    float D[4];
    float mn = FLTMAX, mx = -FLTMAX;
#pragma unroll
    for (int u = 0; u < 4; ++u) {
        int b = tid + u * 256;
        uint4 w = *(const uint4*)&xqb[(i * 1024 + b) * wpr + s * 4];
        int c = __popc(w.x) + __popc(w.y) + __popc(w.z) + __popc(w.w);
        D[u] = __fmul_rn((float)c, 0.3f);
        mn = fminf(mn, D[u]);
        mx = fmaxf(mx, D[u]);
    }
    red[tid] = mn; red[256 + tid] = mx;
    __syncthreads();
    for (int w = 128; w >= 1; w >>= 1) {
        if (tid < w) {
            red[tid] = fminf(red[tid], red[tid + w]);
            red[256 + tid] = fmaxf(red[256 + tid], red[256 + tid + w]);
        }
        __syncthreads();
    }
    mn = red[0]; mx = red[256];
    float step = __fmul_rn(__fsub_rn(mx, mn), 0.03125f);
    if (step <= 0.f) step = 1.f;
#pragma unroll
    for (int u = 0; u < 4; ++u) {
        int b = tid + u * 256;
        float idx = fminf(fmaxf(floorf(__fdiv_rn(__fsub_rn(D[u], mn), step)), 0.f), 31.f);
        Dq[(i * S + s) * 1024 + b] = __fadd_rn(__fmul_rn(idx, step), mn);
    }
}

// dterm[b] = sum_{i,s} Dq[i,s,b] * (85 * 2^i)
__global__ void dterm_kernel(const float* __restrict__ Dq, float* __restrict__ dterm, int S)
{
    int b = blockIdx.x * 256 + threadIdx.x;
    if (b >= 1024) return;
    float sum = 0.f;
    for (int i = 0; i < 8; ++i) {
        float sc = (float)(85 << i);
        for (int s = 0; s < S; ++s) sum = fmaf(Dq[(i * S + s) * 1024 + b], sc, sum);
    }
    dterm[b] = sum;
}

// ---------------------------------------------------------------------------
// Cooperative layer-1: grid 512 (16 b-tiles x 32 f-tiles), 256 threads.
// Block owns a 64b x 16f output tile for ALL (i,k) planes. Per s:
//   stage B(128a x 4k x 16f -> 32KB LDS) + A-bits(8i x 4w x 64b -> 8KB LDS);
//   for each i-half: compute 64 accs (4i x 4k x 4f), plane min/max ->
//   atomicMin/Max, grid.sync, read stats, quantize FROM REGISTERS continuing
//   the exact i-major/k-minor fmaf chain; accR += sum per s.
// P never touches memory. All fp32 chains identical to R5 (absmax 0.0).
// ---------------------------------------------------------------------------
__global__ __launch_bounds__(256, 2) void coop_mm1(
    const unsigned* __restrict__ xqbT, const float* __restrict__ g1t,
    unsigned* __restrict__ stats, float* __restrict__ acc1)
{
    cg::grid_group gridg = cg::this_grid();
    __shared__ __align__(16) float Bs[4][128][16];   // 32 KB
    __shared__ unsigned Aw[8][4][64];                // 8 KB
    __shared__ float wredmn[16][4], wredmx[16][4];
    __shared__ float stf[16][2];                     // (mn, step) per plane
    const int tid = threadIdx.x;
    const int b0 = (blockIdx.x >> 5) * 64;
    const int f0 = (blockIdx.x & 31) * 16;
    const int lane = tid & 63;                       // b within tile
    const int wv = tid >> 6;                         // f4-group (per-wave const)
    const int b = b0 + lane;

    float accR[4] = {0.f, 0.f, 0.f, 0.f};

    for (int s = 0; s < 7; ++s) {
        __syncthreads();
#pragma unroll
        for (int u = 0; u < 8; ++u) {
            int idx = u * 256 + tid;                 // 0..2047
            int k = idx >> 9, a = (idx >> 2) & 127, fg = idx & 3;
            *(float4*)&Bs[k][a][fg * 4] =
                *(const float4*)&g1t[(s * 128 + a) * 2048 + k * 512 + f0 + fg * 4];
            int i = idx >> 8, w = (idx >> 6) & 3, bb = idx & 63;
            Aw[i][w][bb] = xqbT[(i * 28 + s * 4 + w) * 1024 + b0 + bb];
        }
        __syncthreads();

        float sum[4] = {0.f, 0.f, 0.f, 0.f};
        for (int half = 0; half < 2; ++half) {
            float acc[4][4][4] = {};                 // [il][k][j]
            for (int w = 0; w < 4; ++w) {
                unsigned myw[4];
#pragma unroll
                for (int il = 0; il < 4; ++il) myw[il] = Aw[half * 4 + il][w][lane];
#pragma unroll 4
                for (int bit = 0; bit < 32; ++bit) {
                    int a = w * 32 + bit;
                    float4 br0 = *(const float4*)&Bs[0][a][wv * 4];
                    float4 br1 = *(const float4*)&Bs[1][a][wv * 4];
                    float4 br2 = *(const float4*)&Bs[2][a][wv * 4];
                    float4 br3 = *(const float4*)&Bs[3][a][wv * 4];
#pragma unroll
                    for (int il = 0; il < 4; ++il) {
                        float ab = (float)((myw[il] >> bit) & 1u);
                        acc[il][0][0] = fmaf(ab, br0.x, acc[il][0][0]);
                        acc[il][0][1] = fmaf(ab, br0.y, acc[il][0][1]);
                        acc[il][0][2] = fmaf(ab, br0.z, acc[il][0][2]);
                        acc[il][0][3] = fmaf(ab, br0.w, acc[il][0][3]);
                        acc[il][1][0] = fmaf(ab, br1.x, acc[il][1][0]);
                        acc[il][1][1] = fmaf(ab, br1.y, acc[il][1][1]);
                        acc[il][1][2] = fmaf(ab, br1.z, acc[il][1][2]);
                        acc[il][1][3] = fmaf(ab, br1.w, acc[il][1][3]);
                        acc[il][2][0] = fmaf(ab, br2.x, acc[il][2][0]);
                        acc[il][2][1] = fmaf(ab, br2.y, acc[il][2][1]);
                        acc[il][2][2] = fmaf(ab, br2.z, acc[il][2][2]);
                        acc[il][2][3] = fmaf(ab, br2.w, acc[il][2][3]);
                        acc[il][3][0] = fmaf(ab, br3.x, acc[il][3][0]);
                        acc[il][3][1] = fmaf(ab, br3.y, acc[il][3][1]);
                        acc[il][3][2] = fmaf(ab, br3.z, acc[il][3][2]);
                        acc[il][3][3] = fmaf(ab, br3.w, acc[il][3][3]);
                    }
                }
            }
            // per-plane min/max (order-independent): wave reduce then cross-wave
#pragma unroll
            for (int il = 0; il < 4; ++il)
#pragma unroll
                for (int k = 0; k < 4; ++k) {
                    float mn = fminf(fminf(acc[il][k][0], acc[il][k][1]),
                                     fminf(acc[il][k][2], acc[il][k][3]));
                    float mx = fmaxf(fmaxf(acc[il][k][0], acc[il][k][1]),
                                     fmaxf(acc[il][k][2], acc[il][k][3]));
                    for (int off = 32; off >= 1; off >>= 1) {
                        mn = fminf(mn, __shfl_xor(mn, off, 64));
                        mx = fmaxf(mx, __shfl_xor(mx, off, 64));
                    }
                    if (lane == 0) { wredmn[il * 4 + k][wv] = mn; wredmx[il * 4 + k][wv] = mx; }
                }
            __syncthreads();
            if (tid < 16) {
                float mn = fminf(fminf(wredmn[tid][0], wredmn[tid][1]),
                                 fminf(wredmn[tid][2], wredmn[tid][3]));
                float mx = fmaxf(fmaxf(wredmx[tid][0], wredmx[tid][1]),
                                 fmaxf(wredmx[tid][2], wredmx[tid][3]));
                int i = half * 4 + (tid >> 2), k = tid & 3;
                int slot = ((s * 8 + i) * 4 + k) * 2;
                atomicMin(&stats[slot], __float_as_uint(mn));    // P >= 0
                atomicMax(&stats[slot + 1], __float_as_uint(mx));
            }
            __threadfence();
            gridg.sync();
            if (tid < 16) {
                int i = half * 4 + (tid >> 2), k = tid & 3;
                int slot = ((s * 8 + i) * 4 + k) * 2;
                unsigned umn = atomicOr(&stats[slot], 0u);       // device-fresh read
                unsigned umx = atomicOr(&stats[slot + 1], 0u);
                float mn = __uint_as_float(umn), mx = __uint_as_float(umx);
                float step = __fmul_rn(__fsub_rn(mx, mn), 0.03125f);
                if (step <= 0.f) step = 1.f;
                stf[tid][0] = mn; stf[tid][1] = step;
            }
            __syncthreads();
            // quantize from registers, continuing the exact i-major/k-minor chain
#pragma unroll
            for (int il = 0; il < 4; ++il) {
                int i = half * 4 + il;
#pragma unroll
                for (int k = 0; k < 4; ++k) {
                    float mn = stf[il * 4 + k][0], step = stf[il * 4 + k][1];
                    float sc = (float)(1 << (i + 2 * k));
#pragma unroll
                    for (int j = 0; j < 4; ++j) {
                        float ix = fminf(fmaxf(floorf(__fdiv_rn(__fsub_rn(acc[il][k][j], mn),
                                                                step)), 0.f), 31.f);
                        float pq = __fadd_rn(__fmul_rn(ix, step), mn);
                        sum[j] = fmaf(pq, sc, sum[j]);
                    }
                }
            }
        }  // half
#pragma unroll
        for (int j = 0; j < 4; ++j) accR[j] = __fadd_rn(accR[j], sum[j]);
    }  // s

    *(float4*)&acc1[b * 512 + f0 + wv * 4] =
        make_float4(accR[0], accR[1], accR[2], accR[3]);
}

// out1 -> tanh -> xq2 codes; also emit layer-2 bit-planes xqb2 via ballot.
__global__ void finish1_kernel(const float* __restrict__ acc1, const float* __restrict__ dterm1,
                               const float* __restrict__ sx1, float* __restrict__ xq2,
                               unsigned* __restrict__ xqb2)
{
    int gid = blockIdx.x * 256 + threadIdx.x;  // 524288
    int b = gid >> 9, f = gid & 511;
    float total = __fsub_rn(acc1[gid], dterm1[b]);
    float acc = __fdiv_rn(total, 0.9f);
    float o = __fsub_rn(__fdiv_rn(__fmul_rn(2.f, acc), 65025.f), __fdiv_rn(sx1[b], 255.f));
    float h = tanhf(o);
    h = fminf(fmaxf(h, 0.f), 1.f);
    float code = rintf(__fmul_rn(h, 255.f));
    xq2[gid] = code;
    int ci = (int)code;
    int lane = threadIdx.x & 63;
#pragma unroll
    for (int i = 0; i < 8; ++i) {
        unsigned long long m = __ballot((ci >> i) & 1);
        if ((lane & 31) == 0) {
            unsigned wv = (lane & 32) ? (unsigned)(m >> 32) : (unsigned)m;
            xqb2[(i * 1024 + b) * 16 + (f >> 5)] = wv;
        }
    }
}

__global__ void sx2_kernel(const float* __restrict__ xq2, float* __restrict__ sx2)
{
    __shared__ float red[128];
    int b = blockIdx.x;
    float psum = 0.f;
    for (int n = threadIdx.x; n < 512; n += 128) psum += xq2[b * 512 + n];
    red[threadIdx.x] = psum;
    __syncthreads();
    for (int w = 64; w >= 1; w >>= 1) {
        if (threadIdx.x < w) red[threadIdx.x] += red[threadIdx.x + w];
        __syncthreads();
    }
    if (threadIdx.x == 0) sx2[b] = red[0];
}

// Layer-2 matmul: thread per (s,b,f), 32 accumulators (i,k)
__global__ void mm2_kernel(const float* __restrict__ xq2, const float* __restrict__ g2t,
                           float* __restrict__ P2)
{
    int gid = blockIdx.x * 256 + threadIdx.x;  // 40960
    if (gid >= 40960) return;
    int f = gid % 10;
    int b = (gid / 10) & 1023;
    int s = gid / 10240;
    float acc[8][4] = {};
    for (int a = 0; a < 128; ++a) {
        int n = s * 128 + a;
        int xi = (int)xq2[b * 512 + n];
        float g0 = g2t[n * 40 + f];
        float gA = g2t[n * 40 + 10 + f];
        float gB = g2t[n * 40 + 20 + f];
        float gC = g2t[n * 40 + 30 + f];
#pragma unroll
        for (int i = 0; i < 8; ++i) {
            float bi = (float)((xi >> i) & 1);
            acc[i][0] = fmaf(bi, g0, acc[i][0]);
            acc[i][1] = fmaf(bi, gA, acc[i][1]);
            acc[i][2] = fmaf(bi, gB, acc[i][2]);
            acc[i][3] = fmaf(bi, gC, acc[i][3]);
        }
    }
#pragma unroll
    for (int i = 0; i < 8; ++i)
#pragma unroll
        for (int k = 0; k < 4; ++k)
            P2[(size_t)((s * 8 + i) * 4 + k) * 10240 + b * 10 + f] = acc[i][k];
}

__global__ void stat2_kernel(const float* __restrict__ P2, float2* __restrict__ stats2)
{
    __shared__ float red[512];
    int p = blockIdx.x;  // 128 planes
    int tid = threadIdx.x;
    float mn = FLTMAX, mx = -FLTMAX;
    for (int t = tid; t < 10240; t += 256) {
        float v = P2[(size_t)p * 10240 + t];
        mn = fminf(mn, v); mx = fmaxf(mx, v);
    }
    red[tid] = mn; red[256 + tid] = mx;
    __syncthreads();
    for (int w = 128; w >= 1; w >>= 1) {
        if (tid < w) {
            red[tid] = fminf(red[tid], red[tid + w]);
            red[256 + tid] = fmaxf(red[256 + tid], red[256 + tid + w]);
        }
        __syncthreads();
    }
    if (tid == 0) {
        float step = __fmul_rn(__fsub_rn(red[256], red[0]), 0.03125f);
        if (step <= 0.f) step = 1.f;
        stats2[p] = make_float2(red[0], step);
    }
}

__global__ void out2_kernel(const float* __restrict__ P2, const float2* __restrict__ stats2,
                            const float* __restrict__ dterm2, const float* __restrict__ sx2,
                            float* __restrict__ out)
{
    int gid = blockIdx.x * 256 + threadIdx.x;  // 10240
    if (gid >= 10240) return;
    int b = gid / 10;
    float sum = 0.f;
    for (int s = 0; s < 4; ++s)
        for (int i = 0; i < 8; ++i)
#pragma unroll
            for (int k = 0; k < 4; ++k) {
                int p = (s * 8 + i) * 4 + k;
                float2 st = stats2[p];
                float val = P2[(size_t)p * 10240 + gid];
                float idx = fminf(fmaxf(floorf(__fdiv_rn(__fsub_rn(val, st.x), st.y)), 0.f), 31.f);
                float pq = __fadd_rn(__fmul_rn(idx, st.y), st.x);
                sum = fmaf(pq, (float)(1 << (i + 2 * k)), sum);
            }
    float total = __fsub_rn(sum, dterm2[b]);
    float acc = __fdiv_rn(total, 0.9f);
    out[gid] = __fsub_rn(__fdiv_rn(__fmul_rn(2.f, acc), 65025.f), __fdiv_rn(sx2[b], 255.f));
}

extern "C" void kernel_launch(void* const* d_in, const int* in_sizes, int n_in,
                              void* d_out, int out_size, void* d_ws, size_t ws_size,
                              hipStream_t stream)
{
    const float* x      = (const float*)d_in[0];
    const float* w1     = (const float*)d_in[1];
    const float* w3     = (const float*)d_in[2];
    const float* noise1 = (const float*)d_in[3];
    const float* noise3 = (const float*)d_in[4];
    float* out = (float*)d_out;
    float* ws  = (float*)d_ws;

    // ws layout (float offsets)
    float*    xq1    = ws + 0;         // 1024*896
    float*    g1t    = ws + 917504;    // 896*2048
    float*    acc1   = ws + 2752512;   // 1024*512
    float*    xq2    = ws + 3276800;   // 1024*512
    float*    P2     = ws + 3801088;   // 128*10240
    float*    g2t    = ws + 5111808;   // 512*40
    float*    Dq1    = ws + 5132288;   // 56*1024
    float*    Dq2    = ws + 5189632;   // 32*1024
    float*    sx1    = ws + 5222400;   // 1024
    float*    sx2    = ws + 5223424;   // 1024
    float*    dterm1 = ws + 5224448;   // 1024
    float*    dterm2 = ws + 5225472;   // 1024
    float2*   stats2 = (float2*)(ws + 5226496);   // 128 pairs
    unsigned* stats1 = (unsigned*)(ws + 5226752); // 224*2 (pad to 512)
    unsigned* xqbT   = (unsigned*)(ws + 5227264); // 8*28*1024 words
    unsigned* xqb2   = (unsigned*)(ws + 5456640); // 8*1024*16 words

    prep1_kernel<<<1024, 128, 0, stream>>>(x, xq1, sx1, stats1);
    bitpackT_kernel<<<112, 256, 0, stream>>>(xq1, xqbT);
    prepg1t_kernel<<<dim3(28, 16), 256, 0, stream>>>(w1, noise1, g1t);
    dqpopT_kernel<<<56, 256, 0, stream>>>(xqbT, Dq1);
    dterm_kernel<<<4, 256, 0, stream>>>(Dq1, dterm1, 7);

    {
        void* args[] = {(void*)&xqbT, (void*)&g1t, (void*)&stats1, (void*)&acc1};
        hipLaunchCooperativeKernel((const void*)coop_mm1, dim3(512), dim3(256),
                                   args, 0, stream);
    }

    finish1_kernel<<<2048, 256, 0, stream>>>(acc1, dterm1, sx1, xq2, xqb2);
    sx2_kernel<<<1024, 128, 0, stream>>>(xq2, sx2);
    prepg2_kernel<<<20, 256, 0, stream>>>(w3, noise3, g2t);
    dqpop_kernel<<<32, 256, 0, stream>>>(xqb2, Dq2, 4, 16);
    dterm_kernel<<<4, 256, 0, stream>>>(Dq2, dterm2, 4);
    mm2_kernel<<<160, 256, 0, stream>>>(xq2, g2t, P2);
    stat2_kernel<<<128, 256, 0, stream>>>(P2, stats2);
    out2_kernel<<<40, 256, 0, stream>>>(P2, stats2, dterm2, sx2, out);
}

// Round 7
// 670.381 us; speedup vs baseline: 2.5491x; 2.5491x over previous
//
#include <hip/hip_runtime.h>

#define FLTMAX 3.402823466e+38f

// ---------------------------------------------------------------------------
// Geometry:
//   Layer1: B=1024, N=784, Np=896, S=7, F=512, I=8, K=4
//   Layer2: B=1024, N=512, Np=512, S=4, F=10,  I=8, K=4
// P (layer1) is materialized in ws two s-planes at a time (134 MB buffer,
// LLC-resident) -> quant reads hit Infinity Cache, buffer overwritten in-cache.
// ---------------------------------------------------------------------------

// Fused: xq codes (row in LDS) -> sx1 row sum + bit-packed planes xqbT[i][w][b].
// Also initializes stats1 (consumed only after this dispatch completes).
__global__ void prep1_kernel(const float* __restrict__ x, float* __restrict__ sx1,
                             unsigned* __restrict__ xqbT, unsigned* __restrict__ stats1)
{
    __shared__ float xr[896];
    __shared__ float red[128];
    int b = blockIdx.x;
    if (b == 0) {
        for (int t = threadIdx.x; t < 224; t += 128) {
            stats1[t * 2] = 0x7F7FFFFFu; stats1[t * 2 + 1] = 0u;
        }
    }
    float psum = 0.f;
    for (int n = threadIdx.x; n < 896; n += 128) {
        float v = 0.f;
        if (n < 784) {
            float xv = x[b * 784 + n];
            xv = fminf(fmaxf(xv, 0.f), 1.f);
            v = rintf(__fmul_rn(xv, 255.f));
        }
        xr[n] = v;
        psum += v;  // integer-valued, exact in any order
    }
    red[threadIdx.x] = psum;
    __syncthreads();
    for (int w = 64; w >= 1; w >>= 1) {
        if (threadIdx.x < w) red[threadIdx.x] += red[threadIdx.x + w];
        __syncthreads();
    }
    if (threadIdx.x == 0) sx1[b] = red[0];
    if (threadIdx.x < 28) {
        int w = threadIdx.x;
        unsigned words[8] = {0, 0, 0, 0, 0, 0, 0, 0};
#pragma unroll 8
        for (int n = 0; n < 32; ++n) {
            int v = (int)xr[w * 32 + n];
#pragma unroll
            for (int i = 0; i < 8; ++i) words[i] |= ((unsigned)((v >> i) & 1)) << n;
        }
#pragma unroll
        for (int i = 0; i < 8; ++i) xqbT[(i * 28 + w) * 1024 + b] = words[i];
    }
}

// Fused conductance-prep + transpose: writes g1t[n][k*512+f] directly.
__global__ void prepg1t_kernel(const float* __restrict__ w1, const float* __restrict__ noise1,
                               float* __restrict__ g1t)
{
    __shared__ float t[4][32][33];
    const int n0 = blockIdx.x * 32, f0 = blockIdx.y * 32;
    const int tid = threadIdx.x;
    {
        int n = tid & 31, fi = tid >> 5;
#pragma unroll
        for (int p = 0; p < 4; ++p) {
            int f = p * 8 + fi;
            int gn = n0 + n, gf = f0 + f;
            float gv[4] = {0.f, 0.f, 0.f, 0.f};
            if (gn < 784) {
                float w = w1[gf * 784 + gn];
                float Xi = fminf(fmaxf(rintf(__fmul_rn(__fmul_rn(__fadd_rn(w, 1.f), 0.5f), 255.f)),
                                       0.f), 255.f);
                int xi = (int)Xi;
                float4 nz = *(const float4*)&noise1[(gf * 896 + gn) * 4];
                float nzv[4] = {nz.x, nz.y, nz.z, nz.w};
#pragma unroll
                for (int k = 0; k < 4; ++k) {
                    int slc = (xi >> (2 * k)) & 3;
                    float base = __fadd_rn(__fmul_rn((float)slc, 0.9f), 0.3f);
                    float nf = __fadd_rn(1.f, __fmul_rn(0.05f, nzv[k]));
                    gv[k] = __fmul_rn(base, nf);
                }
            }
#pragma unroll
            for (int k = 0; k < 4; ++k) t[k][n][f] = gv[k];
        }
    }
    __syncthreads();
    {
        int f = tid & 31, nn = tid >> 5;
#pragma unroll
        for (int p = 0; p < 4; ++p) {
            int n = p * 8 + nn;
#pragma unroll
            for (int k = 0; k < 4; ++k)
                g1t[(n0 + n) * 2048 + k * 512 + f0 + f] = t[k][n][f];
        }
    }
}

// g2t[n][k][f] layout for layer-2 matmul
__global__ void prepg2_kernel(const float* __restrict__ w3, const float* __restrict__ noise3,
                              float* __restrict__ g2t)
{
    int gid = blockIdx.x * 256 + threadIdx.x;
    if (gid >= 10 * 512) return;
    int f = gid / 512, n = gid % 512;
    float w = w3[f * 512 + n];
    float Xi = fminf(fmaxf(rintf(__fmul_rn(__fmul_rn(__fadd_rn(w, 1.f), 0.5f), 255.f)),
                           0.f), 255.f);
    int xi = (int)Xi;
#pragma unroll
    for (int k = 0; k < 4; ++k) {
        int slc = (xi >> (2 * k)) & 3;
        float base = __fadd_rn(__fmul_rn((float)slc, 0.9f), 0.3f);
        float nf = __fadd_rn(1.f, __fmul_rn(0.05f, noise3[(f * 512 + n) * 4 + k]));
        g2t[n * 40 + k * 10 + f] = __fmul_rn(base, nf);
    }
}

// Layer-1 dummy column from transposed bit-planes: D = 0.3*popc(128 bits).
__global__ void dqpopT_kernel(const unsigned* __restrict__ xqbT, float* __restrict__ Dq)
{
    __shared__ float red[512];
    const int i = blockIdx.x / 7, s = blockIdx.x % 7;
    const int tid = threadIdx.x;
    float D[4];
    float mn = FLTMAX, mx = -FLTMAX;
#pragma unroll
    for (int u = 0; u < 4; ++u) {
        int b = tid + u * 256;
        int c = 0;
#pragma unroll
        for (int w = 0; w < 4; ++w)
            c += __popc(xqbT[(i * 28 + s * 4 + w) * 1024 + b]);
        D[u] = __fmul_rn((float)c, 0.3f);
        mn = fminf(mn, D[u]);
        mx = fmaxf(mx, D[u]);
    }
    red[tid] = mn; red[256 + tid] = mx;
    __syncthreads();
    for (int w = 128; w >= 1; w >>= 1) {
        if (tid < w) {
            red[tid] = fminf(red[tid], red[tid + w]);
            red[256 + tid] = fmaxf(red[256 + tid], red[256 + tid + w]);
        }
        __syncthreads();
    }
    mn = red[0]; mx = red[256];
    float step = __fmul_rn(__fsub_rn(mx, mn), 0.03125f);
    if (step <= 0.f) step = 1.f;
#pragma unroll
    for (int u = 0; u < 4; ++u) {
        int b = tid + u * 256;
        float idx = fminf(fmaxf(floorf(__fdiv_rn(__fsub_rn(D[u], mn), step)), 0.f), 31.f);
        Dq[(i * 7 + s) * 1024 + b] = __fadd_rn(__fmul_rn(idx, step), mn);
    }
}

// Layer-2 dummy column from xqb2 ([i][b][16w] layout).
__global__ void dqpop_kernel(const unsigned* __restrict__ xqb, float* __restrict__ Dq,
                             int S, int wpr)
{
    __shared__ float red[512];
    const int i = blockIdx.x / S, s = blockIdx.x % S;
    const int tid = threadIdx.x;
    float D[4];
    float mn = FLTMAX, mx = -FLTMAX;
#pragma unroll
    for (int u = 0; u < 4; ++u) {
        int b = tid + u * 256;
        uint4 w = *(const uint4*)&xqb[(i * 1024 + b) * wpr + s * 4];
        int c = __popc(w.x) + __popc(w.y) + __popc(w.z) + __popc(w.w);
        D[u] = __fmul_rn((float)c, 0.3f);
        mn = fminf(mn, D[u]);
        mx = fmaxf(mx, D[u]);
    }
    red[tid] = mn; red[256 + tid] = mx;
    __syncthreads();
    for (int w = 128; w >= 1; w >>= 1) {
        if (tid < w) {
            red[tid] = fminf(red[tid], red[tid + w]);
            red[256 + tid] = fmaxf(red[256 + tid], red[256 + tid + w]);
        }
        __syncthreads();
    }
    mn = red[0]; mx = red[256];
    float step = __fmul_rn(__fsub_rn(mx, mn), 0.03125f);
    if (step <= 0.f) step = 1.f;
#pragma unroll
    for (int u = 0; u < 4; ++u) {
        int b = tid + u * 256;
        float idx = fminf(fmaxf(floorf(__fdiv_rn(__fsub_rn(D[u], mn), step)), 0.f), 31.f);
        Dq[(i * S + s) * 1024 + b] = __fadd_rn(__fmul_rn(idx, step), mn);
    }
}

// dterm[b] = sum_{i,s} Dq[i,s,b] * (85 * 2^i)
__global__ void dterm_kernel(const float* __restrict__ Dq, float* __restrict__ dterm, int S)
{
    int b = blockIdx.x * 256 + threadIdx.x;
    if (b >= 1024) return;
    float sum = 0.f;
    for (int i = 0; i < 8; ++i) {
        float sc = (float)(85 << i);
        for (int s = 0; s < S; ++s) sum = fmaf(Dq[(i * S + s) * 1024 + b], sc, sum);
    }
    dterm[b] = sum;
}

// ---------------------------------------------------------------------------
// Layer-1 GEMM, s-grouped (G<=2): grid.x = Gc*64 (sl, i, b-tile), grid.y = 16.
// 128x128 tile, BK=32, 8x8 acc/thread; A from bit-packed words, B in LDS.
// Per-element chain: fmaf over n ascending (bit-exact vs R1..R5).
// ---------------------------------------------------------------------------
#define BK 32
__global__ __launch_bounds__(256, 4) void mm1_kernel(
    const unsigned* __restrict__ xqbT, const float* __restrict__ g1t,
    float* __restrict__ P, unsigned* __restrict__ stats, int s0)
{
    __shared__ __align__(16) float Bs[BK][132];
    __shared__ unsigned Abits[128];
    __shared__ float red[512];
    const int tid = threadIdx.x;
    const int sl = blockIdx.x >> 6;
    const int r = blockIdx.x & 63;
    const int i = r >> 3;
    const int b0 = (r & 7) * 128;
    const int s = s0 + sl;
    const int colBase = blockIdx.y * 128;       // [0, 2048)
    const int tx = tid & 15, ty = tid >> 4;

    const int aB = tid >> 5;          // 0..7  (B rows: u*8 + aB)
    const int eB = (tid & 31) << 2;   // 0..124

    // prefetch chunk 0  (xqbT layout: [i][w][b], w = s*4 + chunk)
    float4 pB[4];
    unsigned pAw = 0;
#pragma unroll
    for (int u = 0; u < 4; ++u)
        pB[u] = *(const float4*)&g1t[(s * 128 + u * 8 + aB) * 2048 + colBase + eB];
    if (tid < 128) pAw = xqbT[(i * 28 + s * 4) * 1024 + b0 + tid];

    float acc[8][8] = {};

    for (int ac = 0; ac < 4; ++ac) {
        __syncthreads();
#pragma unroll
        for (int u = 0; u < 4; ++u)
            *(float4*)&Bs[u * 8 + aB][eB] = pB[u];
        if (tid < 128) Abits[tid] = pAw;
        __syncthreads();

        if (ac < 3) {
            const int n0 = s * 128 + (ac + 1) * BK;
#pragma unroll
            for (int u = 0; u < 4; ++u)
                pB[u] = *(const float4*)&g1t[(n0 + u * 8 + aB) * 2048 + colBase + eB];
            if (tid < 128) pAw = xqbT[(i * 28 + s * 4 + ac + 1) * 1024 + b0 + tid];
        }

        unsigned wrd[8];
#pragma unroll
        for (int u = 0; u < 4; ++u) {
            wrd[u]     = Abits[(ty << 2) + u];
            wrd[4 + u] = Abits[64 + (ty << 2) + u];
        }

#pragma unroll 4
        for (int a = 0; a < BK; ++a) {
            float br[8];
            *(float4*)&br[0] = *(const float4*)&Bs[a][(tx << 2)];
            *(float4*)&br[4] = *(const float4*)&Bs[a][64 + (tx << 2)];
#pragma unroll
            for (int u = 0; u < 8; ++u) {
                float ab = (float)((wrd[u] >> a) & 1u);
#pragma unroll
                for (int v = 0; v < 8; ++v)
                    acc[u][v] = fmaf(ab, br[v], acc[u][v]);
            }
        }
    }

    // store P: rows (sl*8+i)*1024 + b0 + uh*64 + ty*4 + u
#pragma unroll
    for (int uh = 0; uh < 2; ++uh)
#pragma unroll
        for (int u = 0; u < 4; ++u) {
            int row = (sl * 8 + i) * 1024 + b0 + uh * 64 + (ty << 2) + u;
#pragma unroll
            for (int vh = 0; vh < 2; ++vh) {
                float4 v = make_float4(acc[uh * 4 + u][vh * 4 + 0], acc[uh * 4 + u][vh * 4 + 1],
                                       acc[uh * 4 + u][vh * 4 + 2], acc[uh * 4 + u][vh * 4 + 3]);
                *(float4*)&P[(size_t)row * 2048 + colBase + vh * 64 + (tx << 2)] = v;
            }
        }

    float mn = acc[0][0], mx = acc[0][0];
#pragma unroll
    for (int u = 0; u < 8; ++u)
#pragma unroll
        for (int v = 0; v < 8; ++v) { mn = fminf(mn, acc[u][v]); mx = fmaxf(mx, acc[u][v]); }
    red[tid] = mn; red[256 + tid] = mx;
    __syncthreads();
    for (int w = 128; w >= 1; w >>= 1) {
        if (tid < w) {
            red[tid] = fminf(red[tid], red[tid + w]);
            red[256 + tid] = fmaxf(red[256 + tid], red[256 + tid + w]);
        }
        __syncthreads();
    }
    if (tid == 0) {
        int k = colBase >> 9;
        int slot = ((s * 8 + i) * 4 + k) * 2;
        atomicMin(&stats[slot], __float_as_uint(red[0]));      // P >= 0: uint order == float order
        atomicMax(&stats[slot + 1], __float_as_uint(red[256]));
    }
}

// ADC-quantize G s-planes and fold into acc1 with the exact original chain:
// for s ascending: acc1 += (i-outer, k-inner fmaf chain). first => acc1 = .
__global__ void quant1_kernel(const float* __restrict__ P, const unsigned* __restrict__ stats,
                              float* __restrict__ acc1, int s0, int G, int first)
{
    int gid = blockIdx.x * 256 + threadIdx.x;  // 131072
    int b = gid >> 7, f4 = gid & 127;
    float4 accR;
    if (first) accR = make_float4(0.f, 0.f, 0.f, 0.f);
    else       accR = *(const float4*)&acc1[(b << 9) + (f4 << 2)];
    for (int sl = 0; sl < G; ++sl) {
        int s = s0 + sl;
        float4 sum = make_float4(0.f, 0.f, 0.f, 0.f);
        for (int i = 0; i < 8; ++i) {
#pragma unroll
            for (int k = 0; k < 4; ++k) {
                int slot = ((s * 8 + i) * 4 + k) * 2;
                float mn = __uint_as_float(stats[slot]);
                float mx = __uint_as_float(stats[slot + 1]);
                float step = __fmul_rn(__fsub_rn(mx, mn), 0.03125f);
                if (step <= 0.f) step = 1.f;
                float4 val = *(const float4*)&P[(size_t)((sl * 8 + i) * 1024 + b) * 2048
                                                + (k << 9) + (f4 << 2)];
                float sc = (float)(1 << (i + 2 * k));
                float ix, pq;
                ix = fminf(fmaxf(floorf(__fdiv_rn(__fsub_rn(val.x, mn), step)), 0.f), 31.f);
                pq = __fadd_rn(__fmul_rn(ix, step), mn); sum.x = fmaf(pq, sc, sum.x);
                ix = fminf(fmaxf(floorf(__fdiv_rn(__fsub_rn(val.y, mn), step)), 0.f), 31.f);
                pq = __fadd_rn(__fmul_rn(ix, step), mn); sum.y = fmaf(pq, sc, sum.y);
                ix = fminf(fmaxf(floorf(__fdiv_rn(__fsub_rn(val.z, mn), step)), 0.f), 31.f);
                pq = __fadd_rn(__fmul_rn(ix, step), mn); sum.z = fmaf(pq, sc, sum.z);
                ix = fminf(fmaxf(floorf(__fdiv_rn(__fsub_rn(val.w, mn), step)), 0.f), 31.f);
                pq = __fadd_rn(__fmul_rn(ix, step), mn); sum.w = fmaf(pq, sc, sum.w);
            }
        }
        accR.x = __fadd_rn(accR.x, sum.x);
        accR.y = __fadd_rn(accR.y, sum.y);
        accR.z = __fadd_rn(accR.z, sum.z);
        accR.w = __fadd_rn(accR.w, sum.w);
    }
    *(float4*)&acc1[(b << 9) + (f4 << 2)] = accR;
}

// out1 -> tanh -> xq2 codes; emits layer-2 bit-planes xqb2 via ballot and
// sx2 row sum (codes are integers < 2^24: order-exact). Block per b, 512 thr.
__global__ void finish1_kernel(const float* __restrict__ acc1, const float* __restrict__ dterm1,
                               const float* __restrict__ sx1, float* __restrict__ xq2,
                               unsigned* __restrict__ xqb2, float* __restrict__ sx2)
{
    __shared__ float red[512];
    int b = blockIdx.x;
    int f = threadIdx.x;                      // 0..511
    int gid = b * 512 + f;
    float total = __fsub_rn(acc1[gid], dterm1[b]);
    float acc = __fdiv_rn(total, 0.9f);
    float o = __fsub_rn(__fdiv_rn(__fmul_rn(2.f, acc), 65025.f), __fdiv_rn(sx1[b], 255.f));
    float h = tanhf(o);
    h = fminf(fmaxf(h, 0.f), 1.f);
    float code = rintf(__fmul_rn(h, 255.f));
    xq2[gid] = code;
    int ci = (int)code;
    int lane = f & 63;
#pragma unroll
    for (int i = 0; i < 8; ++i) {
        unsigned long long m = __ballot((ci >> i) & 1);
        if ((lane & 31) == 0) {
            unsigned wv = (lane & 32) ? (unsigned)(m >> 32) : (unsigned)m;
            xqb2[(i * 1024 + b) * 16 + (f >> 5)] = wv;
        }
    }
    red[f] = code;
    __syncthreads();
    for (int w = 256; w >= 1; w >>= 1) {
        if (f < w) red[f] += red[f + w];
        __syncthreads();
    }
    if (f == 0) sx2[b] = red[0];
}

// Layer-2 matmul: thread per (s,b,f), 32 accumulators (i,k)
__global__ void mm2_kernel(const float* __restrict__ xq2, const float* __restrict__ g2t,
                           float* __restrict__ P2)
{
    int gid = blockIdx.x * 256 + threadIdx.x;  // 40960
    if (gid >= 40960) return;
    int f = gid % 10;
    int b = (gid / 10) & 1023;
    int s = gid / 10240;
    float acc[8][4] = {};
    for (int a = 0; a < 128; ++a) {
        int n = s * 128 + a;
        int xi = (int)xq2[b * 512 + n];
        float g0 = g2t[n * 40 + f];
        float gA = g2t[n * 40 + 10 + f];
        float gB = g2t[n * 40 + 20 + f];
        float gC = g2t[n * 40 + 30 + f];
#pragma unroll
        for (int i = 0; i < 8; ++i) {
            float bi = (float)((xi >> i) & 1);
            acc[i][0] = fmaf(bi, g0, acc[i][0]);
            acc[i][1] = fmaf(bi, gA, acc[i][1]);
            acc[i][2] = fmaf(bi, gB, acc[i][2]);
            acc[i][3] = fmaf(bi, gC, acc[i][3]);
        }
    }
#pragma unroll
    for (int i = 0; i < 8; ++i)
#pragma unroll
        for (int k = 0; k < 4; ++k)
            P2[(size_t)((s * 8 + i) * 4 + k) * 10240 + b * 10 + f] = acc[i][k];
}

__global__ void stat2_kernel(const float* __restrict__ P2, float2* __restrict__ stats2)
{
    __shared__ float red[512];
    int p = blockIdx.x;  // 128 planes
    int tid = threadIdx.x;
    float mn = FLTMAX, mx = -FLTMAX;
    for (int t = tid; t < 10240; t += 256) {
        float v = P2[(size_t)p * 10240 + t];
        mn = fminf(mn, v); mx = fmaxf(mx, v);
    }
    red[tid] = mn; red[256 + tid] = mx;
    __syncthreads();
    for (int w = 128; w >= 1; w >>= 1) {
        if (tid < w) {
            red[tid] = fminf(red[tid], red[tid + w]);
            red[256 + tid] = fmaxf(red[256 + tid], red[256 + tid + w]);
        }
        __syncthreads();
    }
    if (tid == 0) {
        float step = __fmul_rn(__fsub_rn(red[256], red[0]), 0.03125f);
        if (step <= 0.f) step = 1.f;
        stats2[p] = make_float2(red[0], step);
    }
}

__global__ void out2_kernel(const float* __restrict__ P2, const float2* __restrict__ stats2,
                            const float* __restrict__ dterm2, const float* __restrict__ sx2,
                            float* __restrict__ out)
{
    int gid = blockIdx.x * 256 + threadIdx.x;  // 10240
    if (gid >= 10240) return;
    int b = gid / 10;
    float sum = 0.f;
    for (int s = 0; s < 4; ++s)
        for (int i = 0; i < 8; ++i)
#pragma unroll
            for (int k = 0; k < 4; ++k) {
                int p = (s * 8 + i) * 4 + k;
                float2 st = stats2[p];
                float val = P2[(size_t)p * 10240 + gid];
                float idx = fminf(fmaxf(floorf(__fdiv_rn(__fsub_rn(val, st.x), st.y)), 0.f), 31.f);
                float pq = __fadd_rn(__fmul_rn(idx, st.y), st.x);
                sum = fmaf(pq, (float)(1 << (i + 2 * k)), sum);
            }
    float total = __fsub_rn(sum, dterm2[b]);
    float acc = __fdiv_rn(total, 0.9f);
    out[gid] = __fsub_rn(__fdiv_rn(__fmul_rn(2.f, acc), 65025.f), __fdiv_rn(sx2[b], 255.f));
}

extern "C" void kernel_launch(void* const* d_in, const int* in_sizes, int n_in,
                              void* d_out, int out_size, void* d_ws, size_t ws_size,
                              hipStream_t stream)
{
    const float* x      = (const float*)d_in[0];
    const float* w1     = (const float*)d_in[1];
    const float* w3     = (const float*)d_in[2];
    const float* noise1 = (const float*)d_in[3];
    const float* noise3 = (const float*)d_in[4];
    float* out = (float*)d_out;
    float* ws  = (float*)d_ws;

    // ws layout (float offsets)
    float*    g1t    = ws + 0;         // 896*2048
    float*    acc1   = ws + 1835008;   // 1024*512
    float*    xq2    = ws + 2359296;   // 1024*512
    float*    P2     = ws + 2883584;   // 128*10240
    float*    g2t    = ws + 4194304;   // 512*40
    float*    Dq1    = ws + 4214784;   // 56*1024
    float*    Dq2    = ws + 4272128;   // 32*1024
    float*    sx1    = ws + 4304896;   // 1024
    float*    sx2    = ws + 4305920;   // 1024
    float*    dterm1 = ws + 4306944;   // 1024
    float*    dterm2 = ws + 4307968;   // 1024
    float2*   stats2 = (float2*)(ws + 4308992);   // 128 pairs
    unsigned* stats1 = (unsigned*)(ws + 4309248); // 224*2 (pad to 512)
    unsigned* xqbT   = (unsigned*)(ws + 4309760); // 8*28*1024 words
    unsigned* xqb2   = (unsigned*)(ws + 4539136); // 8*1024*16 words
    float*    Ps     = ws + 4670208;   // G * 8 * 1024 * 2048

    // G=2: 134 MB P buffer stays LLC-resident (256 MB Infinity Cache);
    // quant reads hit LLC, buffer is overwritten in-cache each group.
    const size_t fixedf = 4670208;
    const size_t planef = 16777216;
    int G = ((fixedf + 2 * planef) * sizeof(float) <= ws_size) ? 2 : 1;

    prep1_kernel<<<1024, 128, 0, stream>>>(x, sx1, xqbT, stats1);
    prepg1t_kernel<<<dim3(28, 16), 256, 0, stream>>>(w1, noise1, g1t);
    dqpopT_kernel<<<56, 256, 0, stream>>>(xqbT, Dq1);
    dterm_kernel<<<4, 256, 0, stream>>>(Dq1, dterm1, 7);

    for (int s0 = 0; s0 < 7; s0 += G) {
        int Gc = (7 - s0 < G) ? (7 - s0) : G;
        mm1_kernel<<<dim3(Gc * 64, 16), 256, 0, stream>>>(xqbT, g1t, Ps, stats1, s0);
        quant1_kernel<<<512, 256, 0, stream>>>(Ps, stats1, acc1, s0, Gc, s0 == 0);
    }

    finish1_kernel<<<1024, 512, 0, stream>>>(acc1, dterm1, sx1, xq2, xqb2, sx2);
    prepg2_kernel<<<20, 256, 0, stream>>>(w3, noise3, g2t);
    dqpop_kernel<<<32, 256, 0, stream>>>(xqb2, Dq2, 4, 16);
    dterm_kernel<<<4, 256, 0, stream>>>(Dq2, dterm2, 4);
    mm2_kernel<<<160, 256, 0, stream>>>(xq2, g2t, P2);
    stat2_kernel<<<128, 256, 0, stream>>>(P2, stats2);
    out2_kernel<<<40, 256, 0, stream>>>(P2, stats2, dterm2, sx2, out);
}

// Round 9
// 631.965 us; speedup vs baseline: 2.7040x; 1.0608x over previous
//
#include <hip/hip_runtime.h>

#define FLTMAX 3.402823466e+38f

// ---------------------------------------------------------------------------
// Geometry:
//   Layer1: B=1024, N=784, Np=896, S=7, F=512, I=8, K=4
//   Layer2: B=1024, N=512, Np=512, S=4, F=10,  I=8, K=4
// Layer-1 s-groups sized adaptively (G planes per mm1 dispatch, single P
// buffer). Quant of every group except the last runs standalone; the last
// group's quant is folded into finish1 (same fp32 chain).
// ---------------------------------------------------------------------------

// Fused: xq codes (row in LDS) -> sx1 row sum + bit-packed planes xqbT[i][w][b].
// Also initializes stats1 (consumed only after this dispatch completes).
__global__ void prep1_kernel(const float* __restrict__ x, float* __restrict__ sx1,
                             unsigned* __restrict__ xqbT, unsigned* __restrict__ stats1)
{
    __shared__ float xr[896];
    __shared__ float red[128];
    int b = blockIdx.x;
    if (b == 0) {
        for (int t = threadIdx.x; t < 224; t += 128) {
            stats1[t * 2] = 0x7F7FFFFFu; stats1[t * 2 + 1] = 0u;
        }
    }
    float psum = 0.f;
    for (int n = threadIdx.x; n < 896; n += 128) {
        float v = 0.f;
        if (n < 784) {
            float xv = x[b * 784 + n];
            xv = fminf(fmaxf(xv, 0.f), 1.f);
            v = rintf(__fmul_rn(xv, 255.f));
        }
        xr[n] = v;
        psum += v;  // integer-valued, exact in any order
    }
    red[threadIdx.x] = psum;
    __syncthreads();
    for (int w = 64; w >= 1; w >>= 1) {
        if (threadIdx.x < w) red[threadIdx.x] += red[threadIdx.x + w];
        __syncthreads();
    }
    if (threadIdx.x == 0) sx1[b] = red[0];
    if (threadIdx.x < 28) {
        int w = threadIdx.x;
        unsigned words[8] = {0, 0, 0, 0, 0, 0, 0, 0};
#pragma unroll 8
        for (int n = 0; n < 32; ++n) {
            int v = (int)xr[w * 32 + n];
#pragma unroll
            for (int i = 0; i < 8; ++i) words[i] |= ((unsigned)((v >> i) & 1)) << n;
        }
#pragma unroll
        for (int i = 0; i < 8; ++i) xqbT[(i * 28 + w) * 1024 + b] = words[i];
    }
}

// Fused conductance-prep + transpose: writes g1t[n][k*512+f] directly.
__global__ void prepg1t_kernel(const float* __restrict__ w1, const float* __restrict__ noise1,
                               float* __restrict__ g1t)
{
    __shared__ float t[4][32][33];
    const int n0 = blockIdx.x * 32, f0 = blockIdx.y * 32;
    const int tid = threadIdx.x;
    {
        int n = tid & 31, fi = tid >> 5;
#pragma unroll
        for (int p = 0; p < 4; ++p) {
            int f = p * 8 + fi;
            int gn = n0 + n, gf = f0 + f;
            float gv[4] = {0.f, 0.f, 0.f, 0.f};
            if (gn < 784) {
                float w = w1[gf * 784 + gn];
                float Xi = fminf(fmaxf(rintf(__fmul_rn(__fmul_rn(__fadd_rn(w, 1.f), 0.5f), 255.f)),
                                       0.f), 255.f);
                int xi = (int)Xi;
                float4 nz = *(const float4*)&noise1[(gf * 896 + gn) * 4];
                float nzv[4] = {nz.x, nz.y, nz.z, nz.w};
#pragma unroll
                for (int k = 0; k < 4; ++k) {
                    int slc = (xi >> (2 * k)) & 3;
                    float base = __fadd_rn(__fmul_rn((float)slc, 0.9f), 0.3f);
                    float nf = __fadd_rn(1.f, __fmul_rn(0.05f, nzv[k]));
                    gv[k] = __fmul_rn(base, nf);
                }
            }
#pragma unroll
            for (int k = 0; k < 4; ++k) t[k][n][f] = gv[k];
        }
    }
    __syncthreads();
    {
        int f = tid & 31, nn = tid >> 5;
#pragma unroll
        for (int p = 0; p < 4; ++p) {
            int n = p * 8 + nn;
#pragma unroll
            for (int k = 0; k < 4; ++k)
                g1t[(n0 + n) * 2048 + k * 512 + f0 + f] = t[k][n][f];
        }
    }
}

// g2t[n][k][f] layout for layer-2 matmul
__global__ void prepg2_kernel(const float* __restrict__ w3, const float* __restrict__ noise3,
                              float* __restrict__ g2t)
{
    int gid = blockIdx.x * 256 + threadIdx.x;
    if (gid >= 10 * 512) return;
    int f = gid / 512, n = gid % 512;
    float w = w3[f * 512 + n];
    float Xi = fminf(fmaxf(rintf(__fmul_rn(__fmul_rn(__fadd_rn(w, 1.f), 0.5f), 255.f)),
                           0.f), 255.f);
    int xi = (int)Xi;
#pragma unroll
    for (int k = 0; k < 4; ++k) {
        int slc = (xi >> (2 * k)) & 3;
        float base = __fadd_rn(__fmul_rn((float)slc, 0.9f), 0.3f);
        float nf = __fadd_rn(1.f, __fmul_rn(0.05f, noise3[(f * 512 + n) * 4 + k]));
        g2t[n * 40 + k * 10 + f] = __fmul_rn(base, nf);
    }
}

// Layer-1 dummy column from transposed bit-planes: D = 0.3*popc(128 bits).
__global__ void dqpopT_kernel(const unsigned* __restrict__ xqbT, float* __restrict__ Dq)
{
    __shared__ float red[512];
    const int i = blockIdx.x / 7, s = blockIdx.x % 7;
    const int tid = threadIdx.x;
    float D[4];
    float mn = FLTMAX, mx = -FLTMAX;
#pragma unroll
    for (int u = 0; u < 4; ++u) {
        int b = tid + u * 256;
        int c = 0;
#pragma unroll
        for (int w = 0; w < 4; ++w)
            c += __popc(xqbT[(i * 28 + s * 4 + w) * 1024 + b]);
        D[u] = __fmul_rn((float)c, 0.3f);
        mn = fminf(mn, D[u]);
        mx = fmaxf(mx, D[u]);
    }
    red[tid] = mn; red[256 + tid] = mx;
    __syncthreads();
    for (int w = 128; w >= 1; w >>= 1) {
        if (tid < w) {
            red[tid] = fminf(red[tid], red[tid + w]);
            red[256 + tid] = fmaxf(red[256 + tid], red[256 + tid + w]);
        }
        __syncthreads();
    }
    mn = red[0]; mx = red[256];
    float step = __fmul_rn(__fsub_rn(mx, mn), 0.03125f);
    if (step <= 0.f) step = 1.f;
#pragma unroll
    for (int u = 0; u < 4; ++u) {
        int b = tid + u * 256;
        float idx = fminf(fmaxf(floorf(__fdiv_rn(__fsub_rn(D[u], mn), step)), 0.f), 31.f);
        Dq[(i * 7 + s) * 1024 + b] = __fadd_rn(__fmul_rn(idx, step), mn);
    }
}

// Layer-2 dummy column from xqb2 ([i][b][16w] layout).
__global__ void dqpop_kernel(const unsigned* __restrict__ xqb, float* __restrict__ Dq,
                             int S, int wpr)
{
    __shared__ float red[512];
    const int i = blockIdx.x / S, s = blockIdx.x % S;
    const int tid = threadIdx.x;
    float D[4];
    float mn = FLTMAX, mx = -FLTMAX;
#pragma unroll
    for (int u = 0; u < 4; ++u) {
        int b = tid + u * 256;
        uint4 w = *(const uint4*)&xqb[(i * 1024 + b) * wpr + s * 4];
        int c = __popc(w.x) + __popc(w.y) + __popc(w.z) + __popc(w.w);
        D[u] = __fmul_rn((float)c, 0.3f);
        mn = fminf(mn, D[u]);
        mx = fmaxf(mx, D[u]);
    }
    red[tid] = mn; red[256 + tid] = mx;
    __syncthreads();
    for (int w = 128; w >= 1; w >>= 1) {
        if (tid < w) {
            red[tid] = fminf(red[tid], red[tid + w]);
            red[256 + tid] = fmaxf(red[256 + tid], red[256 + tid + w]);
        }
        __syncthreads();
    }
    mn = red[0]; mx = red[256];
    float step = __fmul_rn(__fsub_rn(mx, mn), 0.03125f);
    if (step <= 0.f) step = 1.f;
#pragma unroll
    for (int u = 0; u < 4; ++u) {
        int b = tid + u * 256;
        float idx = fminf(fmaxf(floorf(__fdiv_rn(__fsub_rn(D[u], mn), step)), 0.f), 31.f);
        Dq[(i * S + s) * 1024 + b] = __fadd_rn(__fmul_rn(idx, step), mn);
    }
}

// ---------------------------------------------------------------------------
// Layer-1 GEMM, s-grouped: grid.x = Gc*64 (sl, i, b-tile), grid.y = 16 (cols).
// 128x128 tile, BK=32, 8x8 acc/thread; A from bit-packed words, B in LDS.
// Per-element chain: fmaf over n ascending (bit-exact vs R1..R7).
// ---------------------------------------------------------------------------
#define BK 32
__global__ __launch_bounds__(256, 4) void mm1_kernel(
    const unsigned* __restrict__ xqbT, const float* __restrict__ g1t,
    float* __restrict__ P, unsigned* __restrict__ stats, int s0)
{
    __shared__ __align__(16) float Bs[BK][132];
    __shared__ unsigned Abits[128];
    __shared__ float red[512];
    const int tid = threadIdx.x;
    const int sl = blockIdx.x >> 6;
    const int r = blockIdx.x & 63;
    const int i = r >> 3;
    const int b0 = (r & 7) * 128;
    const int s = s0 + sl;
    const int colBase = blockIdx.y * 128;       // [0, 2048)
    const int tx = tid & 15, ty = tid >> 4;

    const int aB = tid >> 5;          // 0..7  (B rows: u*8 + aB)
    const int eB = (tid & 31) << 2;   // 0..124

    // prefetch chunk 0  (xqbT layout: [i][w][b], w = s*4 + chunk)
    float4 pB[4];
    unsigned pAw = 0;
#pragma unroll
    for (int u = 0; u < 4; ++u)
        pB[u] = *(const float4*)&g1t[(s * 128 + u * 8 + aB) * 2048 + colBase + eB];
    if (tid < 128) pAw = xqbT[(i * 28 + s * 4) * 1024 + b0 + tid];

    float acc[8][8] = {};

    for (int ac = 0; ac < 4; ++ac) {
        __syncthreads();
#pragma unroll
        for (int u = 0; u < 4; ++u)
            *(float4*)&Bs[u * 8 + aB][eB] = pB[u];
        if (tid < 128) Abits[tid] = pAw;
        __syncthreads();

        if (ac < 3) {
            const int n0 = s * 128 + (ac + 1) * BK;
#pragma unroll
            for (int u = 0; u < 4; ++u)
                pB[u] = *(const float4*)&g1t[(n0 + u * 8 + aB) * 2048 + colBase + eB];
            if (tid < 128) pAw = xqbT[(i * 28 + s * 4 + ac + 1) * 1024 + b0 + tid];
        }

        unsigned wrd[8];
#pragma unroll
        for (int u = 0; u < 4; ++u) {
            wrd[u]     = Abits[(ty << 2) + u];
            wrd[4 + u] = Abits[64 + (ty << 2) + u];
        }

#pragma unroll 4
        for (int a = 0; a < BK; ++a) {
            float br[8];
            *(float4*)&br[0] = *(const float4*)&Bs[a][(tx << 2)];
            *(float4*)&br[4] = *(const float4*)&Bs[a][64 + (tx << 2)];
#pragma unroll
            for (int u = 0; u < 8; ++u) {
                float ab = (float)((wrd[u] >> a) & 1u);
#pragma unroll
                for (int v = 0; v < 8; ++v)
                    acc[u][v] = fmaf(ab, br[v], acc[u][v]);
            }
        }
    }

    // store P: rows (sl*8+i)*1024 + b0 + uh*64 + ty*4 + u
#pragma unroll
    for (int uh = 0; uh < 2; ++uh)
#pragma unroll
        for (int u = 0; u < 4; ++u) {
            int row = (sl * 8 + i) * 1024 + b0 + uh * 64 + (ty << 2) + u;
#pragma unroll
            for (int vh = 0; vh < 2; ++vh) {
                float4 v = make_float4(acc[uh * 4 + u][vh * 4 + 0], acc[uh * 4 + u][vh * 4 + 1],
                                       acc[uh * 4 + u][vh * 4 + 2], acc[uh * 4 + u][vh * 4 + 3]);
                *(float4*)&P[(size_t)row * 2048 + colBase + vh * 64 + (tx << 2)] = v;
            }
        }

    float mn = acc[0][0], mx = acc[0][0];
#pragma unroll
    for (int u = 0; u < 8; ++u)
#pragma unroll
        for (int v = 0; v < 8; ++v) { mn = fminf(mn, acc[u][v]); mx = fmaxf(mx, acc[u][v]); }
    red[tid] = mn; red[256 + tid] = mx;
    __syncthreads();
    for (int w = 128; w >= 1; w >>= 1) {
        if (tid < w) {
            red[tid] = fminf(red[tid], red[tid + w]);
            red[256 + tid] = fmaxf(red[256 + tid], red[256 + tid + w]);
        }
        __syncthreads();
    }
    if (tid == 0) {
        int k = colBase >> 9;
        int slot = ((s * 8 + i) * 4 + k) * 2;
        atomicMin(&stats[slot], __float_as_uint(red[0]));      // P >= 0: uint order == float order
        atomicMax(&stats[slot + 1], __float_as_uint(red[256]));
    }
}

// ADC-quantize G s-planes and fold into acc1 with the exact original chain:
// for s ascending: acc1 += (i-outer, k-inner fmaf chain). first => acc1 = .
__global__ void quant1_kernel(const float* __restrict__ P, const unsigned* __restrict__ stats,
                              float* __restrict__ acc1, int s0, int G, int first)
{
    int gid = blockIdx.x * 256 + threadIdx.x;  // 131072
    int b = gid >> 7, f4 = gid & 127;
    float4 accR;
    if (first) accR = make_float4(0.f, 0.f, 0.f, 0.f);
    else       accR = *(const float4*)&acc1[(b << 9) + (f4 << 2)];
    for (int sl = 0; sl < G; ++sl) {
        int s = s0 + sl;
        float4 sum = make_float4(0.f, 0.f, 0.f, 0.f);
        for (int i = 0; i < 8; ++i) {
#pragma unroll
            for (int k = 0; k < 4; ++k) {
                int slot = ((s * 8 + i) * 4 + k) * 2;
                float mn = __uint_as_float(stats[slot]);
                float mx = __uint_as_float(stats[slot + 1]);
                float step = __fmul_rn(__fsub_rn(mx, mn), 0.03125f);
                if (step <= 0.f) step = 1.f;
                float4 val = *(const float4*)&P[(size_t)((sl * 8 + i) * 1024 + b) * 2048
                                                + (k << 9) + (f4 << 2)];
                float sc = (float)(1 << (i + 2 * k));
                float ix, pq;
                ix = fminf(fmaxf(floorf(__fdiv_rn(__fsub_rn(val.x, mn), step)), 0.f), 31.f);
                pq = __fadd_rn(__fmul_rn(ix, step), mn); sum.x = fmaf(pq, sc, sum.x);
                ix = fminf(fmaxf(floorf(__fdiv_rn(__fsub_rn(val.y, mn), step)), 0.f), 31.f);
                pq = __fadd_rn(__fmul_rn(ix, step), mn); sum.y = fmaf(pq, sc, sum.y);
                ix = fminf(fmaxf(floorf(__fdiv_rn(__fsub_rn(val.z, mn), step)), 0.f), 31.f);
                pq = __fadd_rn(__fmul_rn(ix, step), mn); sum.z = fmaf(pq, sc, sum.z);
                ix = fminf(fmaxf(floorf(__fdiv_rn(__fsub_rn(val.w, mn), step)), 0.f), 31.f);
                pq = __fadd_rn(__fmul_rn(ix, step), mn); sum.w = fmaf(pq, sc, sum.w);
            }
        }
        accR.x = __fadd_rn(accR.x, sum.x);
        accR.y = __fadd_rn(accR.y, sum.y);
        accR.z = __fadd_rn(accR.z, sum.z);
        accR.w = __fadd_rn(accR.w, sum.w);
    }
    *(float4*)&acc1[(b << 9) + (f4 << 2)] = accR;
}

// finish1: inline-quant the LAST s-group (continuing the exact chain), add to
// acc1 partial, subtract inline dterm1, tanh -> xq2 codes; emits layer-2
// bit-planes xqb2 via ballot and sx2 row sum. Block per b, 512 threads.
__global__ void finish1_kernel(const float* __restrict__ acc1, const float* __restrict__ P,
                               const unsigned* __restrict__ stats, int s0, int G, int first,
                               const float* __restrict__ Dq1, const float* __restrict__ sx1,
                               float* __restrict__ xq2, unsigned* __restrict__ xqb2,
                               float* __restrict__ sx2)
{
    __shared__ float red[512];
    __shared__ float dt;
    int b = blockIdx.x;
    int f = threadIdx.x;                      // 0..511
    if (f == 0) {
        float s = 0.f;
        for (int i = 0; i < 8; ++i) {
            float sc = (float)(85 << i);
            for (int ss = 0; ss < 7; ++ss) s = fmaf(Dq1[(i * 7 + ss) * 1024 + b], sc, s);
        }
        dt = s;
    }
    __syncthreads();
    int gid = b * 512 + f;
    float accR = first ? 0.f : acc1[gid];
    for (int sl = 0; sl < G; ++sl) {
        int s = s0 + sl;
        float sum = 0.f;
        for (int i = 0; i < 8; ++i) {
#pragma unroll
            for (int k = 0; k < 4; ++k) {
                int slot = ((s * 8 + i) * 4 + k) * 2;
                float mn = __uint_as_float(stats[slot]);
                float mx = __uint_as_float(stats[slot + 1]);
                float step = __fmul_rn(__fsub_rn(mx, mn), 0.03125f);
                if (step <= 0.f) step = 1.f;
                float val = P[(size_t)((sl * 8 + i) * 1024 + b) * 2048 + (k << 9) + f];
                float ix = fminf(fmaxf(floorf(__fdiv_rn(__fsub_rn(val, mn), step)), 0.f), 31.f);
                float pq = __fadd_rn(__fmul_rn(ix, step), mn);
                sum = fmaf(pq, (float)(1 << (i + 2 * k)), sum);
            }
        }
        accR = __fadd_rn(accR, sum);
    }
    float total = __fsub_rn(accR, dt);
    float acc = __fdiv_rn(total, 0.9f);
    float o = __fsub_rn(__fdiv_rn(__fmul_rn(2.f, acc), 65025.f), __fdiv_rn(sx1[b], 255.f));
    float h = tanhf(o);
    h = fminf(fmaxf(h, 0.f), 1.f);
    float code = rintf(__fmul_rn(h, 255.f));
    xq2[gid] = code;
    int ci = (int)code;
    int lane = f & 63;
#pragma unroll
    for (int i = 0; i < 8; ++i) {
        unsigned long long m = __ballot((ci >> i) & 1);
        if ((lane & 31) == 0) {
            unsigned wv = (lane & 32) ? (unsigned)(m >> 32) : (unsigned)m;
            xqb2[(i * 1024 + b) * 16 + (f >> 5)] = wv;
        }
    }
    red[f] = code;
    __syncthreads();
    for (int w = 256; w >= 1; w >>= 1) {
        if (f < w) red[f] += red[f + w];
        __syncthreads();
    }
    if (f == 0) sx2[b] = red[0];
}

// Layer-2 matmul: thread per (s,b,f), 32 accumulators (i,k)
__global__ void mm2_kernel(const float* __restrict__ xq2, const float* __restrict__ g2t,
                           float* __restrict__ P2)
{
    int gid = blockIdx.x * 256 + threadIdx.x;  // 40960
    if (gid >= 40960) return;
    int f = gid % 10;
    int b = (gid / 10) & 1023;
    int s = gid / 10240;
    float acc[8][4] = {};
    for (int a = 0; a < 128; ++a) {
        int n = s * 128 + a;
        int xi = (int)xq2[b * 512 + n];
        float g0 = g2t[n * 40 + f];
        float gA = g2t[n * 40 + 10 + f];
        float gB = g2t[n * 40 + 20 + f];
        float gC = g2t[n * 40 + 30 + f];
#pragma unroll
        for (int i = 0; i < 8; ++i) {
            float bi = (float)((xi >> i) & 1);
            acc[i][0] = fmaf(bi, g0, acc[i][0]);
            acc[i][1] = fmaf(bi, gA, acc[i][1]);
            acc[i][2] = fmaf(bi, gB, acc[i][2]);
            acc[i][3] = fmaf(bi, gC, acc[i][3]);
        }
    }
#pragma unroll
    for (int i = 0; i < 8; ++i)
#pragma unroll
        for (int k = 0; k < 4; ++k)
            P2[(size_t)((s * 8 + i) * 4 + k) * 10240 + b * 10 + f] = acc[i][k];
}

__global__ void stat2_kernel(const float* __restrict__ P2, float2* __restrict__ stats2)
{
    __shared__ float red[512];
    int p = blockIdx.x;  // 128 planes
    int tid = threadIdx.x;
    float mn = FLTMAX, mx = -FLTMAX;
    for (int t = tid; t < 10240; t += 256) {
        float v = P2[(size_t)p * 10240 + t];
        mn = fminf(mn, v); mx = fmaxf(mx, v);
    }
    red[tid] = mn; red[256 + tid] = mx;
    __syncthreads();
    for (int w = 128; w >= 1; w >>= 1) {
        if (tid < w) {
            red[tid] = fminf(red[tid], red[tid + w]);
            red[256 + tid] = fmaxf(red[256 + tid], red[256 + tid + w]);
        }
        __syncthreads();
    }
    if (tid == 0) {
        float step = __fmul_rn(__fsub_rn(red[256], red[0]), 0.03125f);
        if (step <= 0.f) step = 1.f;
        stats2[p] = make_float2(red[0], step);
    }
}

// dterm2[b] computed inline per thread (exact i-outer/s-inner chain).
__global__ void out2_kernel(const float* __restrict__ P2, const float2* __restrict__ stats2,
                            const float* __restrict__ Dq2, const float* __restrict__ sx2,
                            float* __restrict__ out)
{
    int gid = blockIdx.x * 256 + threadIdx.x;  // 10240
    if (gid >= 10240) return;
    int b = gid / 10;
    float dt = 0.f;
    for (int i = 0; i < 8; ++i) {
        float sc = (float)(85 << i);
        for (int s = 0; s < 4; ++s) dt = fmaf(Dq2[(i * 4 + s) * 1024 + b], sc, dt);
    }
    float sum = 0.f;
    for (int s = 0; s < 4; ++s)
        for (int i = 0; i < 8; ++i)
#pragma unroll
            for (int k = 0; k < 4; ++k) {
                int p = (s * 8 + i) * 4 + k;
                float2 st = stats2[p];
                float val = P2[(size_t)p * 10240 + gid];
                float idx = fminf(fmaxf(floorf(__fdiv_rn(__fsub_rn(val, st.x), st.y)), 0.f), 31.f);
                float pq = __fadd_rn(__fmul_rn(idx, st.y), st.x);
                sum = fmaf(pq, (float)(1 << (i + 2 * k)), sum);
            }
    float total = __fsub_rn(sum, dt);
    float acc = __fdiv_rn(total, 0.9f);
    out[gid] = __fsub_rn(__fdiv_rn(__fmul_rn(2.f, acc), 65025.f), __fdiv_rn(sx2[b], 255.f));
}

extern "C" void kernel_launch(void* const* d_in, const int* in_sizes, int n_in,
                              void* d_out, int out_size, void* d_ws, size_t ws_size,
                              hipStream_t stream)
{
    const float* x      = (const float*)d_in[0];
    const float* w1     = (const float*)d_in[1];
    const float* w3     = (const float*)d_in[2];
    const float* noise1 = (const float*)d_in[3];
    const float* noise3 = (const float*)d_in[4];
    float* out = (float*)d_out;
    float* ws  = (float*)d_ws;

    // ws layout (float offsets)
    float*    g1t    = ws + 0;         // 896*2048
    float*    acc1   = ws + 1835008;   // 1024*512
    float*    xq2    = ws + 2359296;   // 1024*512
    float*    P2     = ws + 2883584;   // 128*10240
    float*    g2t    = ws + 4194304;   // 512*40
    float*    Dq1    = ws + 4214784;   // 56*1024
    float*    Dq2    = ws + 4272128;   // 32*1024
    float*    sx1    = ws + 4304896;   // 1024
    float*    sx2    = ws + 4305920;   // 1024
    float2*   stats2 = (float2*)(ws + 4306944);   // 128 pairs
    unsigned* stats1 = (unsigned*)(ws + 4307200); // 224*2 (pad to 512)
    unsigned* xqbT   = (unsigned*)(ws + 4307712); // 8*28*1024 words
    unsigned* xqb2   = (unsigned*)(ws + 4537088); // 8*1024*16 words
    float*    Ps     = ws + 4668160;   // G * 8 * 1024 * 2048

    // adaptive group size: as many 67MB P s-planes as ws allows (R5-proven)
    const size_t fixedf = 4668160;
    const size_t planef = 16777216;
    int G = 1;
    while (G < 7 && (fixedf + (size_t)(G + 1) * planef) * sizeof(float) <= ws_size) ++G;

    prep1_kernel<<<1024, 128, 0, stream>>>(x, sx1, xqbT, stats1);
    prepg1t_kernel<<<dim3(28, 16), 256, 0, stream>>>(w1, noise1, g1t);
    dqpopT_kernel<<<56, 256, 0, stream>>>(xqbT, Dq1);

    int lastS0 = 0, lastG = 7, anyQuant = 0;
    for (int s0 = 0; s0 < 7;) {
        int Gc = (7 - s0 < G) ? (7 - s0) : G;
        mm1_kernel<<<dim3(Gc * 64, 16), 256, 0, stream>>>(xqbT, g1t, Ps, stats1, s0);
        if (s0 + Gc < 7) {
            quant1_kernel<<<512, 256, 0, stream>>>(Ps, stats1, acc1, s0, Gc, s0 == 0);
            anyQuant = 1;
        } else {
            lastS0 = s0; lastG = Gc;
        }
        s0 += Gc;
    }

    finish1_kernel<<<1024, 512, 0, stream>>>(acc1, Ps, stats1, lastS0, lastG,
                                             anyQuant ? 0 : 1, Dq1, sx1, xq2, xqb2, sx2);
    prepg2_kernel<<<20, 256, 0, stream>>>(w3, noise3, g2t);
    dqpop_kernel<<<32, 256, 0, stream>>>(xqb2, Dq2, 4, 16);
    mm2_kernel<<<160, 256, 0, stream>>>(xq2, g2t, P2);
    stat2_kernel<<<128, 256, 0, stream>>>(P2, stats2);
    out2_kernel<<<40, 256, 0, stream>>>(P2, stats2, Dq2, sx2, out);
}